// Round 11
// baseline (40936.856 us; speedup 1.0000x reference)
//
#include <hip/hip_runtime.h>
#include <hip/hip_bf16.h>
#include <stdint.h>

#define NCH  256
#define EMB  1024
#define HID  2048
#define SEQL 4096

// ---------------- ws layout (bytes) ----------------
static constexpr size_t EG_OFF   = 0;
static constexpr size_t EG_BYTES = (size_t)NCH * 8192 * 4;          // 8,388,608
static constexpr size_t HS_OFF   = EG_OFF + EG_BYTES;
static constexpr size_t HS_BYTES = (size_t)SEQL * HID * 4;          // 33,554,432
static constexpr size_t HB_OFF   = HS_OFF + HS_BYTES;
static constexpr size_t HB_BYTES = 2 * HID * 8;                     // self-tagged u64
static constexpr size_t CF_OFF   = HB_OFF + HB_BYTES;
static constexpr size_t CF_BYTES = HID * 4;
static constexpr size_t WS_NEED  = CF_OFF + CF_BYTES;

// ---------------------------------------------------------------------------
// Kernel A: Eg[c][cu*32 + gate*8 + jl] = bias_g[j] + sum_e emb[c][e]*Wg[e][j]
// ---------------------------------------------------------------------------
__global__ __launch_bounds__(256) void eg_gemm(
    const float* __restrict__ emb,
    const float* __restrict__ Wf, const float* __restrict__ bf,
    const float* __restrict__ Wi, const float* __restrict__ bi,
    const float* __restrict__ Wo, const float* __restrict__ bo,
    const float* __restrict__ Wc, const float* __restrict__ bc,
    float* __restrict__ Eg)
{
    const int nb  = blockIdx.x & 63;
    const int cb  = blockIdx.x >> 6;
    const int tid = threadIdx.x;
    const int col = tid & 127;
    const int gate = col >> 5;
    const int jj   = col & 31;
    const int j    = nb * 32 + jj;
    const int mh   = tid >> 7;

    __shared__ float embT[32][65];
    __shared__ float Wt[32][128];

    float acc[32];
#pragma unroll
    for (int m = 0; m < 32; ++m) acc[m] = 0.f;

    for (int k0 = 0; k0 < EMB; k0 += 32) {
        __syncthreads();
        for (int i = tid; i < 64 * 32; i += 256) {
            int c = i >> 5, kk = i & 31;
            embT[kk][c] = emb[(size_t)(cb * 64 + c) * EMB + k0 + kk];
        }
        for (int i = tid; i < 32 * 128; i += 256) {
            int kk = i >> 7, cl = i & 127;
            int g2 = cl >> 5;
            int jx = nb * 32 + (cl & 31);
            const float* Wp = (g2 == 0) ? Wf : (g2 == 1) ? Wi : (g2 == 2) ? Wo : Wc;
            Wt[kk][cl] = Wp[(size_t)(k0 + kk) * HID + jx];
        }
        __syncthreads();
#pragma unroll 8
        for (int kk = 0; kk < 32; ++kk) {
            float w = Wt[kk][col];
#pragma unroll
            for (int m = 0; m < 32; ++m)
                acc[m] += embT[kk][mh * 32 + m] * w;
        }
    }
    const float* bias = (gate == 0) ? bf : (gate == 1) ? bi : (gate == 2) ? bo : bc;
    float bv = bias[j];
    for (int m = 0; m < 32; ++m) {
        int c = cb * 64 + mh * 32 + m;
        Eg[(size_t)c * 8192 + (j >> 3) * 32 + gate * 8 + (j & 7)] = acc[m] + bv;
    }
}

// ---------------------------------------------------------------------------
// Kernel B: persistent sequential LSTM.
// R11 = R10's design with the fetch-offset bug fixed:
//   each wave-0 lane owns u64 indices [lane*32, lane*32+32) = 256 B; the 16
//   dwordx4 loads must use offset q*16 (0..240). R10 used q*32 -> half the
//   tags unchecked, lane 63 read OOB into cfin -> tag never reached tgt ->
//   infinite spin -> 600 s timeout. Bulk loads use sc0 sc1 (L1+L2 bypass,
//   R8/R9-proven fresh; sc1-only can re-hit a stale L1 line forever).
//  Design under test (unchanged from R10):
//   1. publish via atomic_exchange (RMW executes at the coherence point)
//   2. single-fetcher consume: only wave 0 polls/fetches (256 waves polling
//      instead of 131K threads -> kills per-line service queueing)
// ---------------------------------------------------------------------------
#define REP32(M) M(0) M(1) M(2) M(3) M(4) M(5) M(6) M(7) M(8) M(9) M(10) M(11) \
  M(12) M(13) M(14) M(15) M(16) M(17) M(18) M(19) M(20) M(21) M(22) M(23)      \
  M(24) M(25) M(26) M(27) M(28) M(29) M(30) M(31)

#define REP16(M) M(0) M(1) M(2) M(3) M(4) M(5) M(6) M(7) M(8) M(9) M(10) M(11) \
  M(12) M(13) M(14) M(15)

__global__ __launch_bounds__(512, 2) void lstm_seq(
    const int*   __restrict__ seq,
    const float* __restrict__ h0,
    const float* __restrict__ c0,
    const float* __restrict__ Wf, const float* __restrict__ Wi,
    const float* __restrict__ Wo, const float* __restrict__ Wc,
    const float* __restrict__ Eg,
    float* __restrict__ Hs,
    unsigned long long* hb2, float* cfin)
{
    const int cu   = blockIdx.x;      // 0..255
    const int tid  = threadIdx.x;     // 0..511
    const int lane = tid & 63;
    const int wave = tid >> 6;        // 0..7
    const int g    = lane >> 4;       // gate 0..3 (f,i,o,c)
    const int kp   = lane & 15;       // k-interleave slot
    const int jcol = cu * 8 + wave;   // this wave's output column

    const float* W = (g == 0) ? Wf : (g == 1) ? Wi : (g == 2) ? Wo : Wc;

    // ---- 128 recurrent weights in named registers ----
    // row(i,q) = 1024 + (i*16+kp)*4 + q  -> offset from Wb: (i*64+q)*HID
    const float* Wb = W + (size_t)(1024 + kp * 4) * HID + jcol;
#define WDECL(i) float4 w##i;
    REP32(WDECL)
#undef WDECL
#define WLOAD(i) { w##i.x = Wb[(size_t)((i)*64+0)*HID]; \
                   w##i.y = Wb[(size_t)((i)*64+1)*HID]; \
                   w##i.z = Wb[(size_t)((i)*64+2)*HID]; \
                   w##i.w = Wb[(size_t)((i)*64+3)*HID]; }
    REP32(WLOAD)
#undef WLOAD

    __shared__ __align__(16) float h_lds[2][HID];   // double buffer: 16 KB
    __shared__ int seq_lds[SEQL];                   // 16 KB

    for (int i = tid; i < SEQL; i += 512) seq_lds[i] = seq[i];
    for (int i = tid; i < HID;  i += 512) h_lds[0][i] = h0[i];
    float c = c0[jcol];               // replicated across lanes
    __syncthreads();

    for (int t = 0; t < SEQL; ++t) {
        // ---- Eg for this wave's column ----
        float egv = Eg[(size_t)seq_lds[t] * 8192 + cu * 32 + g * 8 + wave];

        // ---- matvec: 128 MACs/lane from registers, h from LDS buffer t&1 ----
        const float4* hp = (const float4*)(h_lds[t & 1]);
        float accv[4] = {0.f, 0.f, 0.f, 0.f};
#define WMAC(i) { float4 hv = hp[(i)*16 + kp]; \
                  accv[(i)&3] += w##i.x*hv.x + w##i.y*hv.y + w##i.z*hv.z + w##i.w*hv.w; }
        REP32(WMAC)
#undef WMAC
        float sum = (accv[0] + accv[1]) + (accv[2] + accv[3]);

        // ---- intra-wave reduce over the 16 k-slots ----
        sum += __shfl_xor(sum, 1, 16);
        sum += __shfl_xor(sum, 2, 16);
        sum += __shfl_xor(sum, 4, 16);
        sum += __shfl_xor(sum, 8, 16);

        // ---- activation per gate group ----
        float pre = sum + egv;
        float act;
        if (g < 3) {
            act = 1.f / (1.f + __expf(-pre));
        } else {
            float e = __expf(2.f * pre);
            act = 1.f - 2.f / (e + 1.f);
        }
        float f_ = __shfl(act, 0,  64);
        float i_ = __shfl(act, 16, 64);
        float o_ = __shfl(act, 32, 64);
        float g_ = __shfl(act, 48, 64);

        // ---- cell update, replicated on all lanes ----
        c = f_ * c + i_ * g_;
        float e2 = __expf(2.f * c);
        float hn = o_ * (1.f - 2.f / (e2 + 1.f));

        const unsigned tgt  = (unsigned)(t + 1);
        const unsigned bsel = (unsigned)((t + 1) & 1);

        // ---- publish: atomic exchange executes AT the L3 coherence point ----
        if (lane == 0) {
            Hs[(size_t)t * HID + jcol] = hn;
            unsigned long long pk =
                ((unsigned long long)tgt << 32) |
                (unsigned long long)__float_as_uint(hn);
            (void)__hip_atomic_exchange(&hb2[(size_t)bsel * HID + jcol], pk,
                                        __ATOMIC_RELAXED,
                                        __HIP_MEMORY_SCOPE_AGENT);
        }

        // ---- single-fetcher consume: wave 0 gathers all 2048 u64 -> LDS ----
        if (t + 1 < SEQL) {
            if (wave == 0) {
                // lane owns u64 indices [lane*32, lane*32+32) = 256 B
                const unsigned long long* bp =
                    hb2 + (size_t)bsel * HID + (size_t)lane * 32;
#define VDECL(q) uint4 v##q;
                REP16(VDECL)
#undef VDECL
                for (;;) {
                    asm volatile(
                        "global_load_dwordx4 %0,  %16, off sc0 sc1\n\t"
                        "global_load_dwordx4 %1,  %16, off offset:16 sc0 sc1\n\t"
                        "global_load_dwordx4 %2,  %16, off offset:32 sc0 sc1\n\t"
                        "global_load_dwordx4 %3,  %16, off offset:48 sc0 sc1\n\t"
                        "global_load_dwordx4 %4,  %16, off offset:64 sc0 sc1\n\t"
                        "global_load_dwordx4 %5,  %16, off offset:80 sc0 sc1\n\t"
                        "global_load_dwordx4 %6,  %16, off offset:96 sc0 sc1\n\t"
                        "global_load_dwordx4 %7,  %16, off offset:112 sc0 sc1\n\t"
                        "global_load_dwordx4 %8,  %16, off offset:128 sc0 sc1\n\t"
                        "global_load_dwordx4 %9,  %16, off offset:144 sc0 sc1\n\t"
                        "global_load_dwordx4 %10, %16, off offset:160 sc0 sc1\n\t"
                        "global_load_dwordx4 %11, %16, off offset:176 sc0 sc1\n\t"
                        "global_load_dwordx4 %12, %16, off offset:192 sc0 sc1\n\t"
                        "global_load_dwordx4 %13, %16, off offset:208 sc0 sc1\n\t"
                        "global_load_dwordx4 %14, %16, off offset:224 sc0 sc1\n\t"
                        "global_load_dwordx4 %15, %16, off offset:240 sc0 sc1\n\t"
                        "s_waitcnt vmcnt(0)"
                        : "=&v"(v0), "=&v"(v1), "=&v"(v2), "=&v"(v3),
                          "=&v"(v4), "=&v"(v5), "=&v"(v6), "=&v"(v7),
                          "=&v"(v8), "=&v"(v9), "=&v"(v10), "=&v"(v11),
                          "=&v"(v12), "=&v"(v13), "=&v"(v14), "=&v"(v15)
                        : "v"(bp)
                        : "memory");
                    unsigned m = v0.y;
#define MM(q) m = (v##q.y < m) ? v##q.y : m; m = (v##q.w < m) ? v##q.w : m;
                    REP16(MM)
#undef MM
                    if (m >= tgt) break;
                    __builtin_amdgcn_s_sleep(1);
                }
                // stage: load q covers h columns lane*32 + 2q, +1
                float2* dst = (float2*)(h_lds[bsel]) + lane * 16;
#define ST(q) dst[q] = make_float2(__uint_as_float(v##q.x), \
                                   __uint_as_float(v##q.z));
                REP16(ST)
#undef ST
            }
            __syncthreads();            // h(t+1) staged; also closes step t
        }
    }

    if (lane == 0) cfin[jcol] = c;
}

// ---------------------------------------------------------------------------
// Kernel C: preds = Hs @ Wy + by
// ---------------------------------------------------------------------------
__global__ __launch_bounds__(256) void y_gemm(
    const float* __restrict__ Hs, const float* __restrict__ Wy,
    const float* __restrict__ by, float* __restrict__ out)
{
    const int rb  = blockIdx.x * 16;
    const int tid = threadIdx.x;
    __shared__ float A[16][68];
    float acc[16];
#pragma unroll
    for (int r = 0; r < 16; ++r) acc[r] = 0.f;

    for (int k0 = 0; k0 < HID; k0 += 64) {
        __syncthreads();
        for (int i = tid; i < 16 * 64; i += 256) {
            int r = i >> 6, kk = i & 63;
            A[r][kk] = Hs[(size_t)(rb + r) * HID + k0 + kk];
        }
        __syncthreads();
#pragma unroll 8
        for (int kk = 0; kk < 64; ++kk) {
            float b = Wy[(size_t)(k0 + kk) * NCH + tid];
#pragma unroll
            for (int r = 0; r < 16; ++r) acc[r] += A[r][kk] * b;
        }
    }
    float bv = by[tid];
    for (int r = 0; r < 16; ++r)
        out[(size_t)(rb + r) * NCH + tid] = acc[r] + bv;
}

// ---------------------------------------------------------------------------
__global__ void fin_copy(const float* __restrict__ Hs,
                         const float* __restrict__ cfin,
                         float* __restrict__ out)
{
    int i = blockIdx.x * 256 + threadIdx.x;
    if (i < HID)
        out[(size_t)SEQL * NCH + i] = Hs[(size_t)(SEQL - 1) * HID + i];
    else
        out[(size_t)SEQL * NCH + i] = cfin[i - HID];
}

// ---------------------------------------------------------------------------
extern "C" void kernel_launch(void* const* d_in, const int* in_sizes, int n_in,
                              void* d_out, int out_size, void* d_ws, size_t ws_size,
                              hipStream_t stream)
{
    if (n_in < 14 || ws_size < WS_NEED) return;

    const int*   seq = (const int*)  d_in[0];
    const float* h0  = (const float*)d_in[1];
    const float* c0  = (const float*)d_in[2];
    const float* emb = (const float*)d_in[3];
    const float* Wf  = (const float*)d_in[4];
    const float* bf  = (const float*)d_in[5];
    const float* Wi  = (const float*)d_in[6];
    const float* bi  = (const float*)d_in[7];
    const float* Wo  = (const float*)d_in[8];
    const float* bo  = (const float*)d_in[9];
    const float* Wc  = (const float*)d_in[10];
    const float* bc  = (const float*)d_in[11];
    const float* Wy  = (const float*)d_in[12];
    const float* by  = (const float*)d_in[13];

    char* ws = (char*)d_ws;
    float*              Eg   = (float*)(ws + EG_OFF);
    float*              Hs   = (float*)(ws + HS_OFF);
    unsigned long long* hb2  = (unsigned long long*)(ws + HB_OFF);
    float*              cfin = (float*)(ws + CF_OFF);
    float*              out  = (float*)d_out;

    // clear self-tagged exchange buffer every call (poison/stale tags)
    hipMemsetAsync(hb2, 0, HB_BYTES, stream);

    eg_gemm<<<256, 256, 0, stream>>>(emb, Wf, bf, Wi, bi, Wo, bo, Wc, bc, Eg);

    lstm_seq<<<256, 512, 0, stream>>>(seq, h0, c0, Wf, Wi, Wo, Wc, Eg,
                                      Hs, hb2, cfin);

    y_gemm<<<256, 256, 0, stream>>>(Hs, Wy, by, out);

    fin_copy<<<16, 256, 0, stream>>>(Hs, cfin, out);
}

// Round 12
// 26958.578 us; speedup vs baseline: 1.5185x; 1.5185x over previous
//
#include <hip/hip_runtime.h>
#include <hip/hip_bf16.h>
#include <stdint.h>

#define NCH  256
#define EMB  1024
#define HID  2048
#define SEQL 4096

// ---------------- ws layout (bytes) ----------------
static constexpr size_t EG_OFF   = 0;
static constexpr size_t EG_BYTES = (size_t)NCH * 8192 * 4;          // 8,388,608
static constexpr size_t HS_OFF   = EG_OFF + EG_BYTES;
static constexpr size_t HS_BYTES = (size_t)SEQL * HID * 4;          // 33,554,432
static constexpr size_t HB_OFF   = HS_OFF + HS_BYTES;
// 8 replicas x 2 slots x 2048 self-tagged u64
static constexpr size_t HB_BYTES = (size_t)8 * 2 * HID * 8;         // 262,144
static constexpr size_t CF_OFF   = HB_OFF + HB_BYTES;
static constexpr size_t CF_BYTES = HID * 4;
static constexpr size_t WS_NEED  = CF_OFF + CF_BYTES;

// ---------------------------------------------------------------------------
// Kernel A: Eg[c][cu*32 + gate*8 + jl] = bias_g[j] + sum_e emb[c][e]*Wg[e][j]
// ---------------------------------------------------------------------------
__global__ __launch_bounds__(256) void eg_gemm(
    const float* __restrict__ emb,
    const float* __restrict__ Wf, const float* __restrict__ bf,
    const float* __restrict__ Wi, const float* __restrict__ bi,
    const float* __restrict__ Wo, const float* __restrict__ bo,
    const float* __restrict__ Wc, const float* __restrict__ bc,
    float* __restrict__ Eg)
{
    const int nb  = blockIdx.x & 63;
    const int cb  = blockIdx.x >> 6;
    const int tid = threadIdx.x;
    const int col = tid & 127;
    const int gate = col >> 5;
    const int jj   = col & 31;
    const int j    = nb * 32 + jj;
    const int mh   = tid >> 7;

    __shared__ float embT[32][65];
    __shared__ float Wt[32][128];

    float acc[32];
#pragma unroll
    for (int m = 0; m < 32; ++m) acc[m] = 0.f;

    for (int k0 = 0; k0 < EMB; k0 += 32) {
        __syncthreads();
        for (int i = tid; i < 64 * 32; i += 256) {
            int c = i >> 5, kk = i & 31;
            embT[kk][c] = emb[(size_t)(cb * 64 + c) * EMB + k0 + kk];
        }
        for (int i = tid; i < 32 * 128; i += 256) {
            int kk = i >> 7, cl = i & 127;
            int g2 = cl >> 5;
            int jx = nb * 32 + (cl & 31);
            const float* Wp = (g2 == 0) ? Wf : (g2 == 1) ? Wi : (g2 == 2) ? Wo : Wc;
            Wt[kk][cl] = Wp[(size_t)(k0 + kk) * HID + jx];
        }
        __syncthreads();
#pragma unroll 8
        for (int kk = 0; kk < 32; ++kk) {
            float w = Wt[kk][col];
#pragma unroll
            for (int m = 0; m < 32; ++m)
                acc[m] += embT[kk][mh * 32 + m] * w;
        }
    }
    const float* bias = (gate == 0) ? bf : (gate == 1) ? bi : (gate == 2) ? bo : bc;
    float bv = bias[j];
    for (int m = 0; m < 32; ++m) {
        int c = cb * 64 + mh * 32 + m;
        Eg[(size_t)c * 8192 + (j >> 3) * 32 + gate * 8 + (j & 7)] = acc[m] + bv;
    }
}

// ---------------------------------------------------------------------------
// Kernel B: persistent sequential LSTM, 8x-REPLICATED self-tagged exchange.
// Invariant found in R6-R11: every design made all 256 CUs read EVERY line of
// one shared 16KB buffer each step (~512 reader-txns/line/step racing the
// producer's write for the line's L3 service queue -> write visibility delayed
// behind the read queue; transport/hops/publish-flavor all changed nothing).
// R12: producer lanes 0-7 store the self-tagged u64 (tag<<32|h) into 8
// REPLICA buffers (tag travels with data: no vmcnt, no ordering dance).
// Consumer group g=cu&7 reads only replica g -> per-line readers 512 -> 64.
// Busy-spin (no s_sleep: sleep-park re-arbitration is a straggler-jitter
// candidate); polls are compiler agent-scope u64 atomic loads (L3-serviced,
// R6-proven; keeps spin traffic off HBM). One barrier/step.
// ---------------------------------------------------------------------------
#define REP32(M) M(0) M(1) M(2) M(3) M(4) M(5) M(6) M(7) M(8) M(9) M(10) M(11) \
  M(12) M(13) M(14) M(15) M(16) M(17) M(18) M(19) M(20) M(21) M(22) M(23)      \
  M(24) M(25) M(26) M(27) M(28) M(29) M(30) M(31)

__global__ __launch_bounds__(512, 2) void lstm_seq(
    const int*   __restrict__ seq,
    const float* __restrict__ h0,
    const float* __restrict__ c0,
    const float* __restrict__ Wf, const float* __restrict__ Wi,
    const float* __restrict__ Wo, const float* __restrict__ Wc,
    const float* __restrict__ Eg,
    float* __restrict__ Hs,
    unsigned long long* hb2, float* cfin)
{
    const int cu   = blockIdx.x;      // 0..255
    const int tid  = threadIdx.x;     // 0..511
    const int lane = tid & 63;
    const int wave = tid >> 6;        // 0..7
    const int g    = lane >> 4;       // gate 0..3 (f,i,o,c)
    const int kp   = lane & 15;       // k-interleave slot
    const int jcol = cu * 8 + wave;   // this wave's output column
    const int grp  = cu & 7;          // consumer replica group

    const float* W = (g == 0) ? Wf : (g == 1) ? Wi : (g == 2) ? Wo : Wc;

    // ---- 128 recurrent weights in named registers ----
    // row(i,q) = 1024 + (i*16+kp)*4 + q  -> offset from Wb: (i*64+q)*HID
    const float* Wb = W + (size_t)(1024 + kp * 4) * HID + jcol;
#define WDECL(i) float4 w##i;
    REP32(WDECL)
#undef WDECL
#define WLOAD(i) { w##i.x = Wb[(size_t)((i)*64+0)*HID]; \
                   w##i.y = Wb[(size_t)((i)*64+1)*HID]; \
                   w##i.z = Wb[(size_t)((i)*64+2)*HID]; \
                   w##i.w = Wb[(size_t)((i)*64+3)*HID]; }
    REP32(WLOAD)
#undef WLOAD

    __shared__ __align__(16) float h_lds[2][HID];   // double buffer: 16 KB
    __shared__ int seq_lds[SEQL];                   // 16 KB

    for (int i = tid; i < SEQL; i += 512) seq_lds[i] = seq[i];
    for (int i = tid; i < HID;  i += 512) h_lds[0][i] = h0[i];
    float c = c0[jcol];               // replicated across lanes
    __syncthreads();

    for (int t = 0; t < SEQL; ++t) {
        // ---- Eg for this wave's column ----
        float egv = Eg[(size_t)seq_lds[t] * 8192 + cu * 32 + g * 8 + wave];

        // ---- matvec: 128 MACs/lane from registers, h from LDS buffer t&1 ----
        const float4* hp = (const float4*)(h_lds[t & 1]);
        float accv[4] = {0.f, 0.f, 0.f, 0.f};
#define WMAC(i) { float4 hv = hp[(i)*16 + kp]; \
                  accv[(i)&3] += w##i.x*hv.x + w##i.y*hv.y + w##i.z*hv.z + w##i.w*hv.w; }
        REP32(WMAC)
#undef WMAC
        float sum = (accv[0] + accv[1]) + (accv[2] + accv[3]);

        // ---- intra-wave reduce over the 16 k-slots ----
        sum += __shfl_xor(sum, 1, 16);
        sum += __shfl_xor(sum, 2, 16);
        sum += __shfl_xor(sum, 4, 16);
        sum += __shfl_xor(sum, 8, 16);

        // ---- activation per gate group ----
        float pre = sum + egv;
        float act;
        if (g < 3) {
            act = 1.f / (1.f + __expf(-pre));
        } else {
            float e = __expf(2.f * pre);
            act = 1.f - 2.f / (e + 1.f);
        }
        float f_ = __shfl(act, 0,  64);
        float i_ = __shfl(act, 16, 64);
        float o_ = __shfl(act, 32, 64);
        float g_ = __shfl(act, 48, 64);

        // ---- cell update, replicated on all lanes ----
        c = f_ * c + i_ * g_;
        float e2 = __expf(2.f * c);
        float hn = o_ * (1.f - 2.f / (e2 + 1.f));

        const unsigned tgt  = (unsigned)(t + 1);
        const unsigned bsel = (unsigned)((t + 1) & 1);

        // ---- publish to all 8 replicas: lane r stores to replica r ----
        {
            unsigned long long pk =
                ((unsigned long long)tgt << 32) |
                (unsigned long long)__float_as_uint(hn);
            if (lane < 8)
                __hip_atomic_store(
                    &hb2[((size_t)lane * 2 + bsel) * HID + jcol], pk,
                    __ATOMIC_RELAXED, __HIP_MEMORY_SCOPE_AGENT);
        }
        // Hs store off the publish path
        if (lane == 0)
            Hs[(size_t)t * HID + jcol] = hn;

        // ---- consume from replica grp only: thread owns u64 4*tid..4*tid+3 ----
        if (t + 1 < SEQL) {
            const unsigned long long* mp =
                hb2 + ((size_t)grp * 2 + bsel) * HID + 4 * (size_t)tid;
            unsigned long long x0, x1, x2, x3;
            // busy-spin, 4 loads in flight per pass, L3-serviced
            do {
                x0 = __hip_atomic_load(mp + 0, __ATOMIC_RELAXED,
                                       __HIP_MEMORY_SCOPE_AGENT);
                x1 = __hip_atomic_load(mp + 1, __ATOMIC_RELAXED,
                                       __HIP_MEMORY_SCOPE_AGENT);
                x2 = __hip_atomic_load(mp + 2, __ATOMIC_RELAXED,
                                       __HIP_MEMORY_SCOPE_AGENT);
                x3 = __hip_atomic_load(mp + 3, __ATOMIC_RELAXED,
                                       __HIP_MEMORY_SCOPE_AGENT);
            } while ((unsigned)(x0 >> 32) < tgt || (unsigned)(x1 >> 32) < tgt ||
                     (unsigned)(x2 >> 32) < tgt || (unsigned)(x3 >> 32) < tgt);

            float4 hv;
            hv.x = __uint_as_float((unsigned)x0);
            hv.y = __uint_as_float((unsigned)x1);
            hv.z = __uint_as_float((unsigned)x2);
            hv.w = __uint_as_float((unsigned)x3);
            ((float4*)h_lds[bsel])[tid] = hv;
            __syncthreads();            // h(t+1) staged; closes step t
        }
    }

    if (lane == 0) cfin[jcol] = c;
}

// ---------------------------------------------------------------------------
// Kernel C: preds = Hs @ Wy + by
// ---------------------------------------------------------------------------
__global__ __launch_bounds__(256) void y_gemm(
    const float* __restrict__ Hs, const float* __restrict__ Wy,
    const float* __restrict__ by, float* __restrict__ out)
{
    const int rb  = blockIdx.x * 16;
    const int tid = threadIdx.x;
    __shared__ float A[16][68];
    float acc[16];
#pragma unroll
    for (int r = 0; r < 16; ++r) acc[r] = 0.f;

    for (int k0 = 0; k0 < HID; k0 += 64) {
        __syncthreads();
        for (int i = tid; i < 16 * 64; i += 256) {
            int r = i >> 6, kk = i & 63;
            A[r][kk] = Hs[(size_t)(rb + r) * HID + k0 + kk];
        }
        __syncthreads();
#pragma unroll 8
        for (int kk = 0; kk < 64; ++kk) {
            float b = Wy[(size_t)(k0 + kk) * NCH + tid];
#pragma unroll
            for (int r = 0; r < 16; ++r) acc[r] += A[r][kk] * b;
        }
    }
    float bv = by[tid];
    for (int r = 0; r < 16; ++r)
        out[(size_t)(rb + r) * NCH + tid] = acc[r] + bv;
}

// ---------------------------------------------------------------------------
__global__ void fin_copy(const float* __restrict__ Hs,
                         const float* __restrict__ cfin,
                         float* __restrict__ out)
{
    int i = blockIdx.x * 256 + threadIdx.x;
    if (i < HID)
        out[(size_t)SEQL * NCH + i] = Hs[(size_t)(SEQL - 1) * HID + i];
    else
        out[(size_t)SEQL * NCH + i] = cfin[i - HID];
}

// ---------------------------------------------------------------------------
extern "C" void kernel_launch(void* const* d_in, const int* in_sizes, int n_in,
                              void* d_out, int out_size, void* d_ws, size_t ws_size,
                              hipStream_t stream)
{
    if (n_in < 14 || ws_size < WS_NEED) return;

    const int*   seq = (const int*)  d_in[0];
    const float* h0  = (const float*)d_in[1];
    const float* c0  = (const float*)d_in[2];
    const float* emb = (const float*)d_in[3];
    const float* Wf  = (const float*)d_in[4];
    const float* bf  = (const float*)d_in[5];
    const float* Wi  = (const float*)d_in[6];
    const float* bi  = (const float*)d_in[7];
    const float* Wo  = (const float*)d_in[8];
    const float* bo  = (const float*)d_in[9];
    const float* Wc  = (const float*)d_in[10];
    const float* bc  = (const float*)d_in[11];
    const float* Wy  = (const float*)d_in[12];
    const float* by  = (const float*)d_in[13];

    char* ws = (char*)d_ws;
    float*              Eg   = (float*)(ws + EG_OFF);
    float*              Hs   = (float*)(ws + HS_OFF);
    unsigned long long* hb2  = (unsigned long long*)(ws + HB_OFF);
    float*              cfin = (float*)(ws + CF_OFF);
    float*              out  = (float*)d_out;

    // clear replicated exchange buffer every call (poison/stale tags)
    hipMemsetAsync(hb2, 0, HB_BYTES, stream);

    eg_gemm<<<256, 256, 0, stream>>>(emb, Wf, bf, Wi, bi, Wo, bo, Wc, bc, Eg);

    lstm_seq<<<256, 512, 0, stream>>>(seq, h0, c0, Wf, Wi, Wo, Wc, Eg,
                                      Hs, hb2, cfin);

    y_gemm<<<256, 256, 0, stream>>>(Hs, Wy, by, out);

    fin_copy<<<16, 256, 0, stream>>>(Hs, cfin, out);
}